// Round 9
// baseline (147.159 us; speedup 1.0000x reference)
//
#include <hip/hip_runtime.h>

#define B 2
#define N 64
#define D 256
#define H 8
#define DK 32
#define M (B * N * N) // 8192

typedef __attribute__((ext_vector_type(8))) short bf16x8;
typedef __attribute__((ext_vector_type(4))) float f32x4;

// fused projection buffer column offsets (elements, row stride 1024)
#define OFF_LK 0
#define OFF_RK 256
#define OFF_LV 512
#define OFF_RV 768

__device__ __forceinline__ ushort f2b(float f) {
    union { float f; unsigned u; } v; v.f = f;
    unsigned r = v.u + 0x7fffu + ((v.u >> 16) & 1u); // RNE
    return (ushort)(r >> 16);
}
__device__ __forceinline__ float b2f(ushort u) {
    union { unsigned u; float f; } v; v.u = ((unsigned)u) << 16; return v.f;
}
// convert 8 bf16 (packed in a float4 register) to 8 floats
__device__ __forceinline__ void cvt8(float4 raw, float* f) {
    const ushort* s = (const ushort*)&raw;
#pragma unroll
    for (int j = 0; j < 8; ++j) f[j] = b2f(s[j]);
}

// async 16B/lane global->LDS (dst = wave-uniform base + lane*16)
__device__ __forceinline__ void glds16(const ushort* g, ushort* l) {
    __builtin_amdgcn_global_load_lds(
        (const __attribute__((address_space(1))) unsigned int*)g,
        (__attribute__((address_space(3))) unsigned int*)l, 16, 0, 0);
}

// ---------------------------------------------------------------------------
// Cast: state f32 -> bf16; 5 weights -> Wcat[1280][256] bf16; biases -> f32.
// ---------------------------------------------------------------------------
__global__ __launch_bounds__(256) void cast_all(const float* __restrict__ state,
                                                const float* __restrict__ W_lk, const float* __restrict__ W_rk,
                                                const float* __restrict__ W_lv, const float* __restrict__ W_rv,
                                                const float* __restrict__ W_o,
                                                const float* __restrict__ b_lk, const float* __restrict__ b_rk,
                                                const float* __restrict__ b_lv, const float* __restrict__ b_rv,
                                                const float* __restrict__ b_o,
                                                ushort* __restrict__ state_bf,
                                                ushort* __restrict__ Wcat,
                                                float* __restrict__ bias_cat) {
    const int gid = blockIdx.x * 256 + threadIdx.x;
    const float* Ws[5] = {W_lk, W_rk, W_lv, W_rv, W_o};
    const float* bs[5] = {b_lk, b_rk, b_lv, b_rv, b_o};

    if (gid < 1280) bias_cat[gid] = bs[gid >> 8][gid & 255];

    if (gid < 524288) {
        float4 v = *(const float4*)&state[(size_t)gid * 4];
        ushort4 o = {f2b(v.x), f2b(v.y), f2b(v.z), f2b(v.w)};
        *(ushort4*)&state_bf[(size_t)gid * 4] = o;
    } else {
        int u = gid - 524288;            // 0..81919
        int row = u >> 6;                // 0..1279
        int k4 = (u & 63) * 4;
        const float* W = Ws[row >> 8];
        float4 v = *(const float4*)&W[(size_t)(row & 255) * 256 + k4];
        ushort4 o = {f2b(v.x), f2b(v.y), f2b(v.z), f2b(v.w)};
        *(ushort4*)&Wcat[(size_t)row * 256 + k4] = o;
    }
}

// ---------------------------------------------------------------------------
// bf16 MFMA GEMM, m97-style: C[rows, ldc] = A @ Bw^T + bias. 128x128 tile,
// 4 waves, 4x4 16x16x32 frags, BK=32. Staging via global_load_lds width=16.
// ---------------------------------------------------------------------------
template <int BF16OUT>
__global__ __launch_bounds__(256) void gemm_mfma(const ushort* __restrict__ A,
                                                 const ushort* __restrict__ Bw,
                                                 const float* __restrict__ bias,
                                                 void* __restrict__ Cv, int ldc) {
    __shared__ __align__(16) ushort As[128 * 32];
    __shared__ __align__(16) ushort Bs[128 * 32];
    const int tid = threadIdx.x;
    const int lane = tid & 63;
    const int wave = tid >> 6;
    const int wm = (wave & 1) * 64;
    const int wn = (wave >> 1) * 64;
    const int row0 = blockIdx.x * 128;
    const int col0 = blockIdx.y * 128;

    const int lr = lane >> 2;        // 0..15
    const int lkq = (lane & 3) * 8;  // {0,8,16,24}

    const ushort* gA0 = A + (size_t)(row0 + wave * 32 + lr) * 256 + lkq;
    const ushort* gA1 = gA0 + 16 * 256;
    const ushort* gB0 = Bw + (size_t)(col0 + wave * 32 + lr) * 256 + lkq;
    const ushort* gB1 = gB0 + 16 * 256;
    ushort* lA0 = &As[(wave * 32) * 32];
    ushort* lA1 = &As[(wave * 32 + 16) * 32];
    ushort* lB0 = &Bs[(wave * 32) * 32];
    ushort* lB1 = &Bs[(wave * 32 + 16) * 32];

    const int fr = lane & 15;
    const int fk = (lane >> 4) * 8;

    f32x4 acc[4][4] = {};

    for (int k0 = 0; k0 < 256; k0 += 32) {
        __syncthreads();
        glds16(gA0 + k0, lA0);
        glds16(gA1 + k0, lA1);
        glds16(gB0 + k0, lB0);
        glds16(gB1 + k0, lB1);
        __syncthreads();

        bf16x8 af[4], bf[4];
#pragma unroll
        for (int i = 0; i < 4; ++i)
            af[i] = *(const bf16x8*)&As[(wm + i * 16 + fr) * 32 + fk];
#pragma unroll
        for (int j = 0; j < 4; ++j)
            bf[j] = *(const bf16x8*)&Bs[(wn + j * 16 + fr) * 32 + fk];
#pragma unroll
        for (int i = 0; i < 4; ++i)
#pragma unroll
            for (int j = 0; j < 4; ++j)
                acc[i][j] = __builtin_amdgcn_mfma_f32_16x16x32_bf16(af[i], bf[j], acc[i][j], 0, 0, 0);
    }

#pragma unroll
    for (int j = 0; j < 4; ++j) {
        const int col = col0 + wn + j * 16 + (lane & 15);
        const float bv = bias[col];
#pragma unroll
        for (int i = 0; i < 4; ++i) {
            const int rbase = row0 + wm + i * 16 + (lane >> 4) * 4;
#pragma unroll
            for (int r = 0; r < 4; ++r) {
                float o = acc[i][j][r] + bv;
                if (BF16OUT) ((ushort*)Cv)[(size_t)(rbase + r) * ldc + col] = f2b(o);
                else ((float*)Cv)[(size_t)(rbase + r) * ldc + col] = o;
            }
        }
    }
}

// ---------------------------------------------------------------------------
// FUSED scores + online-softmax + gated combine, v4.
// Tile = 16x x 16y per (b,h); grid (4,4,16) = 256 blocks, 512 threads (8 waves).
// a-chunk = 8 (8 iterations x 4 barriers) -> LDS ~77.5 KB -> 2 blocks/CU,
// 16 waves/CU: barrier stalls of one block are hidden by the other.
// Layouts (conflict-audited, all <=2-way):
//   LKs/RKs bf16 [8a][16r][32d] unpadded  (glds16-staged, m97 frag layout)
//   LVs/RVs f32  [8a][16r][44]            (stride 44: even stores, 2-way reads)
//   atts f32 [8a][16x][20y]
// Phases/chunk: stage (wave w stages a=w) -> scores (1 MFMA/wave) ->
//   softmax (threads 0..255) -> gate (thread = (wave:2x, y2:4y, dp:2d)).
// ---------------------------------------------------------------------------
__global__ __launch_bounds__(512, 4) void fused_attn(const ushort* __restrict__ P,
                                                     const unsigned char* __restrict__ mask,
                                                     ushort* __restrict__ xbuf) {
    __shared__ __align__(16) ushort LKs[8 * 16 * 32];
    __shared__ __align__(16) ushort RKs[8 * 16 * 32];
    __shared__ __align__(16) float LVs[8 * 16 * 44];
    __shared__ __align__(16) float RVs[8 * 16 * 44];
    __shared__ __align__(16) float atts[8 * 16 * 20];
    __shared__ __align__(16) unsigned char masks[16 * 8 * 16]; // [x][a][y]
    __shared__ float mstate[16 * 20];
    __shared__ float lstate[16 * 20];
    __shared__ float alphas[16 * 20];

    const int bh = blockIdx.z;
    const int b = bh >> 3, h = bh & 7;
    const int x0 = blockIdx.x * 16, y0 = blockIdx.y * 16;
    const int tid = threadIdx.x;
    const int lane = tid & 63, wave = tid >> 6;

    // gate coords: x = wave*2 + i, y = y2*4 + j, d = 2*dp + {0,1}
    const int y2 = (tid >> 4) & 3, dp = tid & 15;
    // softmax coords (threads 0..255)
    const int sx = tid >> 4, sy = tid & 15;
    if (tid < 256) {
        mstate[sx * 20 + sy] = -3.0e38f;
        lstate[sx * 20 + sy] = 0.0f;
    }

    float2 acc[2][4] = {};
    const float scale = 0.17677669529663687f; // 1/sqrt(32)

    for (int ac = 0; ac < N; ac += 8) {
        __syncthreads();
        // ---- stage: LK/RK via glds (wave w -> a = w), LV/RV f32, mask ----
        {
            const int xl = lane >> 2;          // row within 16-row segment
            const int qb = (lane & 3) * 8;     // 16B quarter (bf16 elements)
            glds16(&P[(((size_t)b * N + x0 + xl) * N + ac + wave) * 1024 + OFF_LK + h * DK + qb],
                   &LKs[wave * 16 * 32]);
            glds16(&P[(((size_t)b * N + ac + wave) * N + y0 + xl) * 1024 + OFF_RK + h * DK + qb],
                   &RKs[wave * 16 * 32]);

            const int row = tid >> 2;               // a*16 + r  (0..127)
            const int q = tid & 3;                  // 8-element slice
            const int a = row >> 4, r = row & 15;
            float f[8];
            cvt8(*(const float4*)&P[(((size_t)b * N + x0 + r) * N + ac + a) * 1024 + OFF_LV + h * DK + q * 8], f);
            *(float4*)&LVs[row * 44 + q * 8]     = make_float4(f[0], f[1], f[2], f[3]);
            *(float4*)&LVs[row * 44 + q * 8 + 4] = make_float4(f[4], f[5], f[6], f[7]);
            cvt8(*(const float4*)&P[(((size_t)b * N + ac + a) * N + y0 + r) * 1024 + OFF_RV + h * DK + q * 8], f);
            *(float4*)&RVs[row * 44 + q * 8]     = make_float4(f[0], f[1], f[2], f[3]);
            *(float4*)&RVs[row * 44 + q * 8 + 4] = make_float4(f[4], f[5], f[6], f[7]);

            if (tid < 128) {
                const int xm = tid >> 3, am = tid & 7;
                *(int4*)&masks[(xm * 8 + am) * 16] =
                    *(const int4*)&mask[(((size_t)b * N + x0 + xm) * N + ac + am) * N + y0];
            }
        }
        __syncthreads();

        // ---- scores via MFMA: wave w -> a = w ----
        {
            const int fr = lane & 15, fk = (lane >> 4) * 8;
            const int yq = lane & 15, xq = (lane >> 4) * 4;
            const int a = wave;
            bf16x8 af = *(const bf16x8*)&LKs[(a * 16 + fr) * 32 + fk];
            bf16x8 bf = *(const bf16x8*)&RKs[(a * 16 + fr) * 32 + fk];
            f32x4 s = {};
            s = __builtin_amdgcn_mfma_f32_16x16x32_bf16(af, bf, s, 0, 0, 0);
#pragma unroll
            for (int rr = 0; rr < 4; ++rr) {
                const int x = xq + rr;
                float sv = s[rr] * scale;
                if (masks[(x * 8 + a) * 16 + yq]) sv = -1000.0f;
                atts[(a * 16 + x) * 20 + yq] = sv;
            }
        }
        __syncthreads();

        // ---- online softmax over 8-a chunk: threads 0..255 own (sx, sy) ----
        if (tid < 256) {
            float s8[8];
            float mc = -3.0e38f;
#pragma unroll
            for (int a = 0; a < 8; ++a) {
                s8[a] = atts[(a * 16 + sx) * 20 + sy];
                mc = fmaxf(mc, s8[a]);
            }
            const float mold = mstate[sx * 20 + sy];
            const float mnew = fmaxf(mold, mc);
            const float alpha = __expf(mold - mnew);
            float ps = 0.0f;
#pragma unroll
            for (int a = 0; a < 8; ++a) {
                float p = __expf(s8[a] - mnew);
                atts[(a * 16 + sx) * 20 + sy] = p;
                ps += p;
            }
            lstate[sx * 20 + sy] = lstate[sx * 20 + sy] * alpha + ps;
            mstate[sx * 20 + sy] = mnew;
            alphas[sx * 20 + sy] = alpha;
        }
        __syncthreads();

        // ---- rescale + gate ----
#pragma unroll
        for (int i = 0; i < 2; ++i) {
            const int x = wave * 2 + i;
            float4 av = *(const float4*)&alphas[x * 20 + y2 * 4];
            const float* ap = (const float*)&av;
#pragma unroll
            for (int j = 0; j < 4; ++j) {
                acc[i][j].x *= ap[j];
                acc[i][j].y *= ap[j];
            }
        }
#pragma unroll
        for (int a = 0; a < 8; ++a) {
            float2 lv[2], rv[4];
#pragma unroll
            for (int i = 0; i < 2; ++i)
                lv[i] = *(const float2*)&LVs[(a * 16 + wave * 2 + i) * 44 + dp * 2];
#pragma unroll
            for (int j = 0; j < 4; ++j)
                rv[j] = *(const float2*)&RVs[(a * 16 + y2 * 4 + j) * 44 + dp * 2];
#pragma unroll
            for (int i = 0; i < 2; ++i) {
                float4 wv = *(const float4*)&atts[(a * 16 + wave * 2 + i) * 20 + y2 * 4];
                const float* wp = (const float*)&wv;
#pragma unroll
                for (int j = 0; j < 4; ++j) {
                    acc[i][j].x += (wp[j] * lv[i].x) * rv[j].x;
                    acc[i][j].y += (wp[j] * lv[i].y) * rv[j].y;
                }
            }
        }
    }

    // ---- epilogue: divide by l, store bf16 ----
#pragma unroll
    for (int i = 0; i < 2; ++i) {
        const int x = wave * 2 + i;
        float4 lq = *(const float4*)&lstate[x * 20 + y2 * 4];
        const float* lp = (const float*)&lq;
#pragma unroll
        for (int j = 0; j < 4; ++j) {
            const float il = 1.0f / lp[j];
            ushort2 o = {f2b(acc[i][j].x * il), f2b(acc[i][j].y * il)};
            *(ushort2*)&xbuf[(((size_t)b * N + x0 + x) * N + y0 + y2 * 4 + j) * D + h * DK + 2 * dp] = o;
        }
    }
}

// ---------------------------------------------------------------------------
extern "C" void kernel_launch(void* const* d_in, const int* in_sizes, int n_in,
                              void* d_out, int out_size, void* d_ws, size_t ws_size,
                              hipStream_t stream) {
    const float* state = (const float*)d_in[0];
    const unsigned char* mask = (const unsigned char*)d_in[1];
    const float* W_lk = (const float*)d_in[2];
    const float* b_lk = (const float*)d_in[3];
    const float* W_rk = (const float*)d_in[4];
    const float* b_rk = (const float*)d_in[5];
    const float* W_lv = (const float*)d_in[6];
    const float* b_lv = (const float*)d_in[7];
    const float* W_rv = (const float*)d_in[8];
    const float* b_rv = (const float*)d_in[9];
    const float* W_o = (const float*)d_in[10];
    const float* b_o = (const float*)d_in[11];
    float* out = (float*)d_out;

    char* ws = (char*)d_ws;
    ushort* P_bf = (ushort*)ws;                          // 8192*1024 bf16 = 16.8 MB
    ws += (size_t)M * 1024 * 2;
    float* bias_cat = (float*)ws;                        // 1280 f32
    ws += 1280 * 4;
    ushort* state_bf = (ushort*)ws;                      // 4 MB
    ws += (size_t)M * D * 2;
    ushort* Wcat = (ushort*)ws;                          // 0.65 MB
    ws += (size_t)1280 * 256 * 2;
    ushort* xbuf_bf = (ushort*)ws;                       // 4 MB

    cast_all<<<2368, 256, 0, stream>>>(state, W_lk, W_rk, W_lv, W_rv, W_o,
                                       b_lk, b_rk, b_lv, b_rv, b_o,
                                       state_bf, Wcat, bias_cat);
    gemm_mfma<1><<<dim3(M / 128, 8), 256, 0, stream>>>(state_bf, Wcat, bias_cat, P_bf, 1024);
    fused_attn<<<dim3(4, 4, B * H), 512, 0, stream>>>(P_bf, mask, xbuf_bf);
    gemm_mfma<0><<<dim3(M / 128, 2), 256, 0, stream>>>(xbuf_bf, Wcat + 1024 * 256, bias_cat + 1024, out, 256);
}

// Round 10
// 123.455 us; speedup vs baseline: 1.1920x; 1.1920x over previous
//
#include <hip/hip_runtime.h>

#define B 2
#define N 64
#define D 256
#define H 8
#define DK 32
#define M (B * N * N) // 8192

typedef __attribute__((ext_vector_type(8))) short bf16x8;
typedef __attribute__((ext_vector_type(4))) float f32x4;

// P is head-major: 4 proj planes of [b][h][r1*64+r2][32] bf16
#define PROJ_ELEMS (2097152)  // B*H*4096*32

__device__ __forceinline__ ushort f2b(float f) {
    union { float f; unsigned u; } v; v.f = f;
    unsigned r = v.u + 0x7fffu + ((v.u >> 16) & 1u); // RNE
    return (ushort)(r >> 16);
}
__device__ __forceinline__ float b2f(ushort u) {
    union { unsigned u; float f; } v; v.u = ((unsigned)u) << 16; return v.f;
}
// convert 8 bf16 (packed in a float4 register) to 8 floats
__device__ __forceinline__ void cvt8(float4 raw, float* f) {
    const ushort* s = (const ushort*)&raw;
#pragma unroll
    for (int j = 0; j < 8; ++j) f[j] = b2f(s[j]);
}

// async 16B/lane global->LDS (dst = wave-uniform base + lane*16)
__device__ __forceinline__ void glds16(const ushort* g, ushort* l) {
    __builtin_amdgcn_global_load_lds(
        (const __attribute__((address_space(1))) unsigned int*)g,
        (__attribute__((address_space(3))) unsigned int*)l, 16, 0, 0);
}

// ---------------------------------------------------------------------------
// Cast: state f32 -> bf16; 5 weights -> Wcat[1280][256] bf16; biases -> f32.
// ---------------------------------------------------------------------------
__global__ __launch_bounds__(256) void cast_all(const float* __restrict__ state,
                                                const float* __restrict__ W_lk, const float* __restrict__ W_rk,
                                                const float* __restrict__ W_lv, const float* __restrict__ W_rv,
                                                const float* __restrict__ W_o,
                                                const float* __restrict__ b_lk, const float* __restrict__ b_rk,
                                                const float* __restrict__ b_lv, const float* __restrict__ b_rv,
                                                const float* __restrict__ b_o,
                                                ushort* __restrict__ state_bf,
                                                ushort* __restrict__ Wcat,
                                                float* __restrict__ bias_cat) {
    const int gid = blockIdx.x * 256 + threadIdx.x;
    const float* Ws[5] = {W_lk, W_rk, W_lv, W_rv, W_o};
    const float* bs[5] = {b_lk, b_rk, b_lv, b_rv, b_o};

    if (gid < 1280) bias_cat[gid] = bs[gid >> 8][gid & 255];

    if (gid < 524288) {
        float4 v = *(const float4*)&state[(size_t)gid * 4];
        ushort4 o = {f2b(v.x), f2b(v.y), f2b(v.z), f2b(v.w)};
        *(ushort4*)&state_bf[(size_t)gid * 4] = o;
    } else {
        int u = gid - 524288;            // 0..81919
        int row = u >> 6;                // 0..1279
        int k4 = (u & 63) * 4;
        const float* W = Ws[row >> 8];
        float4 v = *(const float4*)&W[(size_t)(row & 255) * 256 + k4];
        ushort4 o = {f2b(v.x), f2b(v.y), f2b(v.z), f2b(v.w)};
        *(ushort4*)&Wcat[(size_t)row * 256 + k4] = o;
    }
}

// ---------------------------------------------------------------------------
// bf16 MFMA GEMM, m97-style. 128x128 tile, 4 waves, 4x4 16x16x32 frags, BK=32.
// RELAYOUT=1 (proj): scatter C into head-major P planes.
// ---------------------------------------------------------------------------
template <int BF16OUT, int RELAYOUT>
__global__ __launch_bounds__(256) void gemm_mfma(const ushort* __restrict__ A,
                                                 const ushort* __restrict__ Bw,
                                                 const float* __restrict__ bias,
                                                 void* __restrict__ Cv, int ldc) {
    __shared__ __align__(16) ushort As[128 * 32];
    __shared__ __align__(16) ushort Bs[128 * 32];
    const int tid = threadIdx.x;
    const int lane = tid & 63;
    const int wave = tid >> 6;
    const int wm = (wave & 1) * 64;
    const int wn = (wave >> 1) * 64;
    const int row0 = blockIdx.x * 128;
    const int col0 = blockIdx.y * 128;

    const int lr = lane >> 2;        // 0..15
    const int lkq = (lane & 3) * 8;  // {0,8,16,24}

    const ushort* gA0 = A + (size_t)(row0 + wave * 32 + lr) * 256 + lkq;
    const ushort* gA1 = gA0 + 16 * 256;
    const ushort* gB0 = Bw + (size_t)(col0 + wave * 32 + lr) * 256 + lkq;
    const ushort* gB1 = gB0 + 16 * 256;
    ushort* lA0 = &As[(wave * 32) * 32];
    ushort* lA1 = &As[(wave * 32 + 16) * 32];
    ushort* lB0 = &Bs[(wave * 32) * 32];
    ushort* lB1 = &Bs[(wave * 32 + 16) * 32];

    const int fr = lane & 15;
    const int fk = (lane >> 4) * 8;

    f32x4 acc[4][4] = {};

    for (int k0 = 0; k0 < 256; k0 += 32) {
        __syncthreads();
        glds16(gA0 + k0, lA0);
        glds16(gA1 + k0, lA1);
        glds16(gB0 + k0, lB0);
        glds16(gB1 + k0, lB1);
        __syncthreads();

        bf16x8 af[4], bf[4];
#pragma unroll
        for (int i = 0; i < 4; ++i)
            af[i] = *(const bf16x8*)&As[(wm + i * 16 + fr) * 32 + fk];
#pragma unroll
        for (int j = 0; j < 4; ++j)
            bf[j] = *(const bf16x8*)&Bs[(wn + j * 16 + fr) * 32 + fk];
#pragma unroll
        for (int i = 0; i < 4; ++i)
#pragma unroll
            for (int j = 0; j < 4; ++j)
                acc[i][j] = __builtin_amdgcn_mfma_f32_16x16x32_bf16(af[i], bf[j], acc[i][j], 0, 0, 0);
    }

#pragma unroll
    for (int j = 0; j < 4; ++j) {
        const int col = col0 + wn + j * 16 + (lane & 15);
        const float bv = bias[col];
#pragma unroll
        for (int i = 0; i < 4; ++i) {
            const int rbase = row0 + wm + i * 16 + (lane >> 4) * 4;
#pragma unroll
            for (int r = 0; r < 4; ++r) {
                float o = acc[i][j][r] + bv;
                if (RELAYOUT) {
                    const int row = rbase + r;
                    const int bb = row >> 12, rr = row & 4095;
                    const int proj = col >> 8, hh = (col >> 5) & 7, dk = col & 31;
                    ((ushort*)Cv)[(size_t)proj * PROJ_ELEMS +
                                  ((size_t)(bb * 8 + hh) * 4096 + rr) * 32 + dk] = f2b(o);
                } else if (BF16OUT) {
                    ((ushort*)Cv)[(size_t)(rbase + r) * ldc + col] = f2b(o);
                } else {
                    ((float*)Cv)[(size_t)(rbase + r) * ldc + col] = o;
                }
            }
        }
    }
}

// ---------------------------------------------------------------------------
// FUSED scores + online-softmax + gated combine, v5.
// Tile = 16x x 16y per (b,h); grid (4,4,16) = 256 blocks, 512 threads (8 waves).
// a-chunk = 16, 3 barriers/chunk. P head-major -> contiguous reads.
// LK/RK: NO LDS — per-lane 16B global loads ARE the MFMA A/B frags.
// mask: direct per-lane byte loads.
// LDS (~112 KB, 1 block/CU): LVs/RVs f32 [16a][16r][44]; atts [16a][16x][20y].
// ---------------------------------------------------------------------------
__global__ __launch_bounds__(512) void fused_attn(const ushort* __restrict__ P,
                                                  const unsigned char* __restrict__ mask,
                                                  ushort* __restrict__ xbuf) {
    __shared__ __align__(16) float LVs[16 * 16 * 44];
    __shared__ __align__(16) float RVs[16 * 16 * 44];
    __shared__ __align__(16) float atts[16 * 16 * 20];
    __shared__ float mstate[16 * 20];
    __shared__ float lstate[16 * 20];
    __shared__ float alphas[16 * 20];

    const int bh = blockIdx.z;
    const int b = bh >> 3, h = bh & 7;
    const int x0 = blockIdx.x * 16, y0 = blockIdx.y * 16;
    const int tid = threadIdx.x;
    const int lane = tid & 63, wave = tid >> 6;

    const size_t HB = (size_t)bh * 4096 * 32;   // head slice offset (elements)
    const ushort* PLK = P + HB;
    const ushort* PRK = P + (size_t)1 * PROJ_ELEMS + HB;
    const ushort* PLV = P + (size_t)2 * PROJ_ELEMS + HB;
    const ushort* PRV = P + (size_t)3 * PROJ_ELEMS + HB;

    // gate coords: x = wave*2 + i, y = y2*4 + j, d = 2*dp + {0,1}
    const int y2 = (tid >> 4) & 3, dp = tid & 15;
    // softmax coords (threads 0..255)
    const int sx = tid >> 4, sy = tid & 15;
    if (tid < 256) {
        mstate[sx * 20 + sy] = -3.0e38f;
        lstate[sx * 20 + sy] = 0.0f;
    }

    float2 acc[2][4] = {};
    const float scale = 0.17677669529663687f; // 1/sqrt(32)

    for (int ac = 0; ac < N; ac += 16) {
        __syncthreads();
        // ---- phase 1a: stage LV/RV (f32, conflict-audited stride 44) ----
#pragma unroll
        for (int it = 0; it < 2; ++it) {
            const int row = (tid >> 2) + it * 128;  // a*16 + r
            const int q = tid & 3;
            const int a = row >> 4, r = row & 15;
            float f[8];
            cvt8(*(const float4*)&PLV[((size_t)(x0 + r) * 64 + ac + a) * 32 + q * 8], f);
            *(float4*)&LVs[row * 44 + q * 8]     = make_float4(f[0], f[1], f[2], f[3]);
            *(float4*)&LVs[row * 44 + q * 8 + 4] = make_float4(f[4], f[5], f[6], f[7]);
            cvt8(*(const float4*)&PRV[((size_t)(ac + a) * 64 + y0 + r) * 32 + q * 8], f);
            *(float4*)&RVs[row * 44 + q * 8]     = make_float4(f[0], f[1], f[2], f[3]);
            *(float4*)&RVs[row * 44 + q * 8 + 4] = make_float4(f[4], f[5], f[6], f[7]);
        }
        // ---- phase 1b: scores — direct global frags + MFMA, mask direct ----
        {
            const int fr = lane & 15, fk = (lane >> 4) * 8;
            const int yq = lane & 15, xq = (lane >> 4) * 4;
#pragma unroll
            for (int aw = 0; aw < 2; ++aw) {
                const int a = wave * 2 + aw;
                bf16x8 af = *(const bf16x8*)&PLK[((size_t)(x0 + fr) * 64 + ac + a) * 32 + fk];
                bf16x8 bf = *(const bf16x8*)&PRK[((size_t)(ac + a) * 64 + y0 + fr) * 32 + fk];
                f32x4 s = {};
                s = __builtin_amdgcn_mfma_f32_16x16x32_bf16(af, bf, s, 0, 0, 0);
#pragma unroll
                for (int rr = 0; rr < 4; ++rr) {
                    const int x = xq + rr;
                    float sv = s[rr] * scale;
                    if (mask[((size_t)(b * N + x0 + x) * N + ac + a) * N + y0 + yq]) sv = -1000.0f;
                    atts[(a * 16 + x) * 20 + yq] = sv;
                }
            }
        }
        __syncthreads();

        // ---- online softmax over 16-a chunk: threads 0..255 own (sx, sy) ----
        if (tid < 256) {
            float s16[16];
            float mc = -3.0e38f;
#pragma unroll
            for (int a = 0; a < 16; ++a) {
                s16[a] = atts[(a * 16 + sx) * 20 + sy];
                mc = fmaxf(mc, s16[a]);
            }
            const float mold = mstate[sx * 20 + sy];
            const float mnew = fmaxf(mold, mc);
            const float alpha = __expf(mold - mnew);
            float ps = 0.0f;
#pragma unroll
            for (int a = 0; a < 16; ++a) {
                float p = __expf(s16[a] - mnew);
                atts[(a * 16 + sx) * 20 + sy] = p;
                ps += p;
            }
            lstate[sx * 20 + sy] = lstate[sx * 20 + sy] * alpha + ps;
            mstate[sx * 20 + sy] = mnew;
            alphas[sx * 20 + sy] = alpha;
        }
        __syncthreads();

        // ---- rescale + gate ----
#pragma unroll
        for (int i = 0; i < 2; ++i) {
            const int x = wave * 2 + i;
            float4 av = *(const float4*)&alphas[x * 20 + y2 * 4];
            const float* ap = (const float*)&av;
#pragma unroll
            for (int j = 0; j < 4; ++j) {
                acc[i][j].x *= ap[j];
                acc[i][j].y *= ap[j];
            }
        }
#pragma unroll
        for (int a = 0; a < 16; ++a) {
            float2 lv[2], rv[4];
#pragma unroll
            for (int i = 0; i < 2; ++i)
                lv[i] = *(const float2*)&LVs[(a * 16 + wave * 2 + i) * 44 + dp * 2];
#pragma unroll
            for (int j = 0; j < 4; ++j)
                rv[j] = *(const float2*)&RVs[(a * 16 + y2 * 4 + j) * 44 + dp * 2];
#pragma unroll
            for (int i = 0; i < 2; ++i) {
                float4 wv = *(const float4*)&atts[(a * 16 + wave * 2 + i) * 20 + y2 * 4];
                const float* wp = (const float*)&wv;
#pragma unroll
                for (int j = 0; j < 4; ++j) {
                    acc[i][j].x += (wp[j] * lv[i].x) * rv[j].x;
                    acc[i][j].y += (wp[j] * lv[i].y) * rv[j].y;
                }
            }
        }
    }

    // ---- epilogue: divide by l, store bf16 ----
#pragma unroll
    for (int i = 0; i < 2; ++i) {
        const int x = wave * 2 + i;
        float4 lq = *(const float4*)&lstate[x * 20 + y2 * 4];
        const float* lp = (const float*)&lq;
#pragma unroll
        for (int j = 0; j < 4; ++j) {
            const float il = 1.0f / lp[j];
            ushort2 o = {f2b(acc[i][j].x * il), f2b(acc[i][j].y * il)};
            *(ushort2*)&xbuf[(((size_t)b * N + x0 + x) * N + y0 + y2 * 4 + j) * D + h * DK + 2 * dp] = o;
        }
    }
}

// ---------------------------------------------------------------------------
extern "C" void kernel_launch(void* const* d_in, const int* in_sizes, int n_in,
                              void* d_out, int out_size, void* d_ws, size_t ws_size,
                              hipStream_t stream) {
    const float* state = (const float*)d_in[0];
    const unsigned char* mask = (const unsigned char*)d_in[1];
    const float* W_lk = (const float*)d_in[2];
    const float* b_lk = (const float*)d_in[3];
    const float* W_rk = (const float*)d_in[4];
    const float* b_rk = (const float*)d_in[5];
    const float* W_lv = (const float*)d_in[6];
    const float* b_lv = (const float*)d_in[7];
    const float* W_rv = (const float*)d_in[8];
    const float* b_rv = (const float*)d_in[9];
    const float* W_o = (const float*)d_in[10];
    const float* b_o = (const float*)d_in[11];
    float* out = (float*)d_out;

    char* ws = (char*)d_ws;
    ushort* P_bf = (ushort*)ws;                          // 4 proj planes, 16.8 MB
    ws += (size_t)4 * PROJ_ELEMS * 2;
    float* bias_cat = (float*)ws;                        // 1280 f32
    ws += 1280 * 4;
    ushort* state_bf = (ushort*)ws;                      // 4 MB
    ws += (size_t)M * D * 2;
    ushort* Wcat = (ushort*)ws;                          // 0.65 MB
    ws += (size_t)1280 * 256 * 2;
    ushort* xbuf_bf = (ushort*)ws;                       // 4 MB

    cast_all<<<2368, 256, 0, stream>>>(state, W_lk, W_rk, W_lv, W_rv, W_o,
                                       b_lk, b_rk, b_lv, b_rv, b_o,
                                       state_bf, Wcat, bias_cat);
    gemm_mfma<1, 1><<<dim3(M / 128, 8), 256, 0, stream>>>(state_bf, Wcat, bias_cat, P_bf, 1024);
    fused_attn<<<dim3(4, 4, B * H), 512, 0, stream>>>(P_bf, mask, xbuf_bf);
    gemm_mfma<0, 0><<<dim3(M / 128, 2), 256, 0, stream>>>(xbuf_bf, Wcat + 1024 * 256, bias_cat + 1024, out, 256);
}